// Round 3
// baseline (1271.896 us; speedup 1.0000x reference)
//
#include <hip/hip_runtime.h>
#include <hip/hip_bf16.h>

#define LOG2E 1.4426950408889634f
#define LN2   0.6931471805599453f
#define NEG2  (-1.4426950e30f)
#define EXP2F(x) __builtin_exp2f(x)
#define LOG2F(x) __builtin_log2f(x)

// ---------------------------------------------------------------------------
// Kernel 1a: log2-softmax denominators for error task (C=8), one row/thread
// ---------------------------------------------------------------------------
__global__ void denom_err_kernel(const float* __restrict__ logits,
                                 float* __restrict__ d2, int rows) {
    int r = blockIdx.x * blockDim.x + threadIdx.x;
    if (r >= rows) return;
    const float* row = logits + (size_t)r * 8;
    float x[8];
#pragma unroll
    for (int i = 0; i < 8; ++i) x[i] = row[i] * LOG2E;
    float m = x[0];
#pragma unroll
    for (int i = 1; i < 8; ++i) m = fmaxf(m, x[i]);
    float s = 0.f;
#pragma unroll
    for (int i = 0; i < 8; ++i) s += EXP2F(x[i] - m);
    d2[r] = m + LOG2F(s);
}

// ---------------------------------------------------------------------------
// Kernel 1b: log2-softmax denominators for phoneme task (C=128), one row/wave
// ---------------------------------------------------------------------------
__global__ void denom_ph_kernel(const float* __restrict__ logits,
                                float* __restrict__ d2, int rows) {
    int wave = (int)((blockIdx.x * (size_t)blockDim.x + threadIdx.x) >> 6);
    int lane = threadIdx.x & 63;
    if (wave >= rows) return;
    const float* row = logits + (size_t)wave * 128;
    float x0 = row[lane] * LOG2E;
    float x1 = row[lane + 64] * LOG2E;
    float m = fmaxf(x0, x1);
#pragma unroll
    for (int i = 1; i < 64; i <<= 1) m = fmaxf(m, __shfl_xor(m, i));
    float s = EXP2F(x0 - m) + EXP2F(x1 - m);
#pragma unroll
    for (int i = 1; i < 64; i <<= 1) s += __shfl_xor(s, i);
    if (lane == 0) d2[wave] = m + LOG2F(s);
}

// ---------------------------------------------------------------------------
// CTC forward: one wave per (task, sample), log2-domain alpha recursion.
// Lane owns NST contiguous states (NST even => state parity static in s).
// Logits staged through a 64-row LDS ring, double-chunk (32 rows per chunk):
// global float4 loads for chunk c+2 issued at start of chunk c, LDS-written at
// its end. Per-step LDS gathers register-prefetched 2 steps ahead.
// ---------------------------------------------------------------------------
template <int NST, int C>
__device__ __forceinline__ void gather_row(const float* ringL, const float* ringD,
                                           int row, const int (&clsoff)[NST],
                                           float (&g)[NST], float& gd) {
    int base = (row & 63) * C;
#pragma unroll
    for (int s = 0; s < NST; ++s) g[s] = ringL[base + clsoff[s]];
    gd = ringD[row & 63];
}

template <int C, int CHV>
__device__ __forceinline__ void stage_load(const float* __restrict__ lrow,
                                           const float* __restrict__ d2row,
                                           int t0, int T, int lane,
                                           float4 (&st)[CHV], float4& stD) {
#pragma unroll
    for (int j = 0; j < CHV; ++j) {
        int e = t0 * C + (j * 64 + lane) * 4;
        e = min(e, T * C - 4);
        st[j] = *(const float4*)(lrow + e);
    }
    if (lane < 8) {
        int e = t0 + lane * 4;
        e = min(e, T - 4);
        stD = *(const float4*)(d2row + e);
    }
}

template <int C, int CHV>
__device__ __forceinline__ void stage_write(float* ringL, float* ringD, int t0, int lane,
                                            const float4 (&st)[CHV], const float4& stD) {
    int base = (t0 & 63) * C;
#pragma unroll
    for (int j = 0; j < CHV; ++j)
        *(float4*)(ringL + base + (j * 64 + lane) * 4) = st[j];
    if (lane < 8)
        *(float4*)(ringD + (t0 & 63) + lane * 4) = stD;
}

template <int NST>
__device__ __forceinline__ void do_step(float (&a)[NST], const float (&g)[NST], float gd,
                                        const bool (&skipb)[NST], int lane, int t,
                                        int t_idx, int l1, int l2,
                                        float& capA, float& capB) {
    float lp[NST];
#pragma unroll
    for (int s = 0; s < NST; ++s) lp[s] = __builtin_fmaf(g[s], LOG2E, -gd);
    float top1 = __shfl_up(a[NST - 1], 1);
    if (lane == 0) top1 = NEG2;
    if (t == 0) {
#pragma unroll
        for (int s = 0; s < NST; ++s) {
            int l = lane * NST + s;
            a[s] = (l < 2) ? lp[s] : NEG2;
        }
    } else {
        float an[NST];
#pragma unroll
        for (int s = 0; s < NST; ++s) {
            float a1 = a[s];
            float a2 = (s == 0) ? top1 : a[s - 1];
            float m, e;
            if ((s & 1) == 0) {          // blank state: no skip transition
                m = fmaxf(a1, a2);
                e = EXP2F(a1 - m) + EXP2F(a2 - m);
            } else {                     // label state
                float a3 = (s == 1) ? top1 : a[s - 2];
                a3 = skipb[s] ? a3 : NEG2;
                m = fmaxf(fmaxf(a1, a2), a3);
                e = EXP2F(a1 - m) + EXP2F(a2 - m) + EXP2F(a3 - m);
            }
            an[s] = m + LOG2F(e) + lp[s];
        }
#pragma unroll
        for (int s = 0; s < NST; ++s) a[s] = an[s];
    }
    if (t == t_idx) {
#pragma unroll
        for (int s = 0; s < NST; ++s) {
            int l = lane * NST + s;
            if (l == l1) capA = a[s];
            if (l == l2) capB = a[s];
        }
    }
}

template <int NST, int C, int S, int CHV>
__device__ __forceinline__ void ctc_run(
    const float* __restrict__ lrow, const float* __restrict__ d2row,
    const int* __restrict__ tgt, int T, int t_idx, int l1, int l2,
    float* ringL, float* ringD, float* __restrict__ loss_out, int b) {
    const int lane = threadIdx.x & 63;
    const int L = 2 * S + 1;

    int clsoff[NST];
    bool skipb[NST];
#pragma unroll
    for (int s = 0; s < NST; ++s) {
        int l = lane * NST + s;
        int li = (l < L) ? l : 0;
        int c = 0;
        bool sk = false;
        if (li & 1) {
            int i = li >> 1;
            c = tgt[i];
            if (li >= 3) sk = (c != tgt[i - 1]);
        }
        clsoff[s] = c;
        skipb[s] = sk;
    }

    float4 st[CHV];
    float4 stD = make_float4(0.f, 0.f, 0.f, 0.f);
    stage_load<C, CHV>(lrow, d2row, 0, T, lane, st, stD);
    stage_write<C, CHV>(ringL, ringD, 0, lane, st, stD);
    stage_load<C, CHV>(lrow, d2row, 32, T, lane, st, stD);
    stage_write<C, CHV>(ringL, ringD, 32, lane, st, stD);
    stage_load<C, CHV>(lrow, d2row, 64, T, lane, st, stD);  // chunk 2 in flight

    float gA[NST], gB[NST], dA, dB;
    gather_row<NST, C>(ringL, ringD, 0, clsoff, gA, dA);
    gather_row<NST, C>(ringL, ringD, 1, clsoff, gB, dB);

    float a[NST];
#pragma unroll
    for (int s = 0; s < NST; ++s) a[s] = NEG2;
    float capA = NEG2, capB = NEG2;

    const int NCH = (T + 31) >> 5;
    for (int c = 0; c < NCH; ++c) {
        int t0 = c << 5;
        int half = min(32, T - t0) >> 1;
        for (int j = 0; j < half; ++j) {
            int t = t0 + 2 * j;
            do_step<NST>(a, gA, dA, skipb, lane, t, t_idx, l1, l2, capA, capB);
            gather_row<NST, C>(ringL, ringD, t + 2, clsoff, gA, dA);
            do_step<NST>(a, gB, dB, skipb, lane, t + 1, t_idx, l1, l2, capA, capB);
            gather_row<NST, C>(ringL, ringD, t + 3, clsoff, gB, dB);
            if (j == 14 && c + 2 < NCH) {
                stage_write<C, CHV>(ringL, ringD, t0 + 64, lane, st, stD);
                if (c + 3 < NCH)
                    stage_load<C, CHV>(lrow, d2row, t0 + 96, T, lane, st, stD);
            }
        }
    }

    float mm = fmaxf(capA, capB);
#pragma unroll
    for (int i = 1; i < 64; i <<= 1) mm = fmaxf(mm, __shfl_xor(mm, i));
    float sum = EXP2F(capA - mm) + EXP2F(capB - mm);
#pragma unroll
    for (int i = 1; i < 64; i <<= 1) sum += __shfl_xor(sum, i);
    if (lane == 0) loss_out[b] = -(mm + LOG2F(sum)) * LN2;
}

__global__ __launch_bounds__(64) void ctc_kernel(
    const float* __restrict__ err_logits, const float* __restrict__ ph_logits,
    const int* __restrict__ err_tgt, const int* __restrict__ ph_tgt,
    const int* __restrict__ err_il, const int* __restrict__ ph_il,
    const int* __restrict__ err_tl, const int* __restrict__ ph_tl,
    const float* __restrict__ d2_err, const float* __restrict__ d2_ph,
    float* __restrict__ loss_err, float* __restrict__ loss_ph, int T) {
    __shared__ float ringL[64 * 128];
    __shared__ float ringD[64];
    int blk = blockIdx.x;
    if (blk < 32) {
        int b = blk;
        const int L = 101;
        int tl = err_tl[b];
        int l1 = min(2 * tl, L - 1);
        int l2 = max(min(2 * tl - 1, L - 1), 0);
        int t_idx = min(max(err_il[b] - 1, 0), T - 1);
        ctc_run<2, 8, 50, 1>(err_logits + (size_t)b * T * 8, d2_err + (size_t)b * T,
                             err_tgt + b * 50, T, t_idx, l1, l2, ringL, ringD,
                             loss_err, b);
    } else {
        int b = blk - 32;
        const int L = 401;
        int tl = ph_tl[b];
        int l1 = min(2 * tl, L - 1);
        int l2 = max(min(2 * tl - 1, L - 1), 0);
        int t_idx = min(max(ph_il[b] - 1, 0), T - 1);
        ctc_run<8, 128, 200, 16>(ph_logits + (size_t)b * T * 128, d2_ph + (size_t)b * T,
                                 ph_tgt + b * 200, T, t_idx, l1, l2, ringL, ringD,
                                 loss_ph, b);
    }
}

// ---------------------------------------------------------------------------
// Kernel 3: focal transform + means + total. One wave.
// ---------------------------------------------------------------------------
__global__ void final_kernel(const float* __restrict__ loss_err,
                             const float* __restrict__ loss_ph,
                             float* __restrict__ out) {
    int lane = threadIdx.x & 63;
    float fe = 0.f, fp = 0.f;
    if (lane < 32) {
        float l = fmaxf(loss_err[lane], 1e-6f);
        float pt = fminf(fmaxf(EXP2F(-l * LOG2E), 1e-6f), 1.0f);
        float om = 1.f - pt;
        fe = om * om * l;
        l = fmaxf(loss_ph[lane], 1e-6f);
        pt = fminf(fmaxf(EXP2F(-l * LOG2E), 1e-6f), 1.0f);
        om = 1.f - pt;
        fp = om * om * l;
    }
#pragma unroll
    for (int i = 1; i < 64; i <<= 1) {
        fe += __shfl_xor(fe, i);
        fp += __shfl_xor(fp, i);
    }
    if (lane == 0) {
        float err = fe / 32.f;
        float ph = fp / 32.f;
        out[0] = err + ph;
        out[1] = err;
        out[2] = ph;
    }
}

// ---------------------------------------------------------------------------
extern "C" void kernel_launch(void* const* d_in, const int* in_sizes, int n_in,
                              void* d_out, int out_size, void* d_ws, size_t ws_size,
                              hipStream_t stream) {
    const int B = 32, T = 2000;
    const float* err_logits = (const float*)d_in[0];  // [32,2000,8]
    const float* ph_logits  = (const float*)d_in[1];  // [32,2000,128]
    const int* err_tgt = (const int*)d_in[2];         // [32,50]
    const int* ph_tgt  = (const int*)d_in[3];         // [32,200]
    const int* err_il  = (const int*)d_in[4];
    const int* ph_il   = (const int*)d_in[5];
    const int* err_tl  = (const int*)d_in[6];
    const int* ph_tl   = (const int*)d_in[7];
    float* out = (float*)d_out;

    float* ws = (float*)d_ws;
    float* d2_err   = ws;                 // 64000
    float* d2_ph    = ws + 64000;         // 64000
    float* loss_err = ws + 128000;        // 32
    float* loss_ph  = ws + 128032;        // 32

    int rows = B * T;  // 64000
    denom_err_kernel<<<(rows + 255) / 256, 256, 0, stream>>>(err_logits, d2_err, rows);
    denom_ph_kernel<<<rows / 4, 256, 0, stream>>>(ph_logits, d2_ph, rows);
    ctc_kernel<<<64, 64, 0, stream>>>(err_logits, ph_logits, err_tgt, ph_tgt,
                                      err_il, ph_il, err_tl, ph_tl,
                                      d2_err, d2_ph, loss_err, loss_ph, T);
    final_kernel<<<1, 64, 0, stream>>>(loss_err, loss_ph, out);
}

// Round 4
// 735.189 us; speedup vs baseline: 1.7300x; 1.7300x over previous
//
#include <hip/hip_runtime.h>
#include <hip/hip_bf16.h>

#define LOG2E 1.4426950408889634f
#define LN2   0.6931471805599453f
#define NEG2  (-1.4426950e30f)
#define EXP2F(x) __builtin_exp2f(x)
#define LOG2F(x) __builtin_log2f(x)
#define LDEXPF(x,k) __builtin_ldexpf((x),(k))

// ---------------------------------------------------------------------------
// Kernel 1a: log2-softmax denominators for error task (C=8), one row/thread
// ---------------------------------------------------------------------------
__global__ void denom_err_kernel(const float* __restrict__ logits,
                                 float* __restrict__ d2, int rows) {
    int r = blockIdx.x * blockDim.x + threadIdx.x;
    if (r >= rows) return;
    const float* row = logits + (size_t)r * 8;
    float x[8];
#pragma unroll
    for (int i = 0; i < 8; ++i) x[i] = row[i] * LOG2E;
    float m = x[0];
#pragma unroll
    for (int i = 1; i < 8; ++i) m = fmaxf(m, x[i]);
    float s = 0.f;
#pragma unroll
    for (int i = 0; i < 8; ++i) s += EXP2F(x[i] - m);
    d2[r] = m + LOG2F(s);
}

// ---------------------------------------------------------------------------
// Kernel 1b: log2-softmax denominators for phoneme task (C=128), one row/wave
// ---------------------------------------------------------------------------
__global__ void denom_ph_kernel(const float* __restrict__ logits,
                                float* __restrict__ d2, int rows) {
    int wave = (int)((blockIdx.x * (size_t)blockDim.x + threadIdx.x) >> 6);
    int lane = threadIdx.x & 63;
    if (wave >= rows) return;
    const float* row = logits + (size_t)wave * 128;
    float x0 = row[lane] * LOG2E;
    float x1 = row[lane + 64] * LOG2E;
    float m = fmaxf(x0, x1);
#pragma unroll
    for (int i = 1; i < 64; i <<= 1) m = fmaxf(m, __shfl_xor(m, i));
    float s = EXP2F(x0 - m) + EXP2F(x1 - m);
#pragma unroll
    for (int i = 1; i < 64; i <<= 1) s += __shfl_xor(s, i);
    if (lane == 0) d2[wave] = m + LOG2F(s);
}

// ---------------------------------------------------------------------------
// CTC forward: one wave per (task, sample). LINEAR-domain alpha recursion with
// per-lane block-float (f32 mantissas + per-lane int exponent E). Cross-lane
// alignment via E' = max(E, E_nbr) and ldexp with <=0 shifts (exact; underflow
// = pruning >126 bits below lane max). Only NST exp2 per step, all off the
// recursion's critical path. Logits staged via 64-row LDS ring (float4 global
// loads issued ~2 chunks ahead), gathers register-prefetched 2 steps ahead.
// ---------------------------------------------------------------------------
template <int NST, int C>
__device__ __forceinline__ void gather_row(const float* ringL, const float* ringD,
                                           int row, const int (&clsoff)[NST],
                                           float (&g)[NST], float& gd) {
    int base = (row & 63) * C;
#pragma unroll
    for (int s = 0; s < NST; ++s) g[s] = ringL[base + clsoff[s]];
    gd = ringD[row & 63];
}

template <int C, int CHV>
__device__ __forceinline__ void stage_load(const float* __restrict__ lrow,
                                           const float* __restrict__ d2row,
                                           int t0, int T, int lane,
                                           float4 (&st)[CHV], float4& stD) {
#pragma unroll
    for (int j = 0; j < CHV; ++j) {
        int e = t0 * C + (j * 64 + lane) * 4;
        e = min(e, T * C - 4);
        st[j] = *(const float4*)(lrow + e);
    }
    if (lane < 8) {
        int e = t0 + lane * 4;
        e = min(e, T - 4);
        stD = *(const float4*)(d2row + e);
    }
}

template <int C, int CHV>
__device__ __forceinline__ void stage_write(float* ringL, float* ringD, int t0, int lane,
                                            const float4 (&st)[CHV], const float4& stD) {
    int base = (t0 & 63) * C;
#pragma unroll
    for (int j = 0; j < CHV; ++j)
        *(float4*)(ringL + base + (j * 64 + lane) * 4) = st[j];
    if (lane < 8)
        *(float4*)(ringD + (t0 & 63) + lane * 4) = stD;
}

template <int NST>
__device__ __forceinline__ void do_step_lin(
    float (&a)[NST], int& E,
    const float (&g)[NST], float gd,
    const float (&validf)[NST], const bool (&skipb)[NST],
    int lane, int t, int t_idx, int l1, int l2,
    float& capA, float& capB, int& capEA, int& capEB) {
    // emission probabilities (off critical path: depend only on gathers)
    float p[NST];
#pragma unroll
    for (int s = 0; s < NST; ++s)
        p[s] = validf[s] * EXP2F(__builtin_fmaf(g[s], LOG2E, -gd));

    if (t == 0) {
#pragma unroll
        for (int s = 0; s < NST; ++s) {
            int l = lane * NST + s;
            a[s] = (l < 2) ? p[s] : 0.f;
        }
        E = 0;
    } else {
        float top1 = __shfl_up(a[NST - 1], 1);
        int   En   = __shfl_up(E, 1);
        if (lane == 0) { top1 = 0.f; En = -0x40000000; }
        int Ep = max(E, En);
        float t1 = LDEXPF(top1, En - Ep);      // shift <= 0 always
        float ao[NST];
#pragma unroll
        for (int s = 0; s < NST; ++s) ao[s] = LDEXPF(a[s], E - Ep);
        E = Ep;
#pragma unroll
        for (int s = 0; s < NST; ++s) {
            float sum;
            if (s == 0)            sum = ao[0] + t1;
            else if (s == 1)       sum = ao[1] + ao[0] + (skipb[1] ? t1 : 0.f);
            else if ((s & 1) == 0) sum = ao[s] + ao[s - 1];
            else                   sum = ao[s] + ao[s - 1] + (skipb[s] ? ao[s - 2] : 0.f);
            a[s] = sum * p[s];
        }
    }

    if (t == t_idx) {
#pragma unroll
        for (int s = 0; s < NST; ++s) {
            int l = lane * NST + s;
            if (l == l1) { capA = a[s]; capEA = E; }
            if (l == l2) { capB = a[s]; capEB = E; }
        }
    }

    if ((t & 1) == 1) {  // per-lane renorm every 2 steps (p<=1: only shrinks)
        float m = a[0];
#pragma unroll
        for (int s = 1; s < NST; ++s) m = fmaxf(m, a[s]);
        int k = ((__float_as_int(m) >> 23) & 255) - 127;
#pragma unroll
        for (int s = 0; s < NST; ++s) a[s] = LDEXPF(a[s], -k);
        E += k;
    }
}

template <int NST, int C, int S, int CHV>
__device__ __forceinline__ void ctc_run(
    const float* __restrict__ lrow, const float* __restrict__ d2row,
    const int* __restrict__ tgt, int T, int t_idx, int l1, int l2,
    float* ringL, float* ringD, float* __restrict__ loss_out, int b) {
    const int lane = threadIdx.x & 63;
    const int L = 2 * S + 1;

    int clsoff[NST];
    bool skipb[NST];
    float validf[NST];
#pragma unroll
    for (int s = 0; s < NST; ++s) {
        int l = lane * NST + s;
        bool v = (l < L);
        int li = v ? l : 0;
        int c = 0;
        bool sk = false;
        if (li & 1) {
            int i = li >> 1;
            c = tgt[i];
            if (li >= 3) sk = (c != tgt[i - 1]);
        }
        clsoff[s] = c;
        skipb[s] = sk;
        validf[s] = v ? 1.f : 0.f;
    }

    float4 st[CHV];
    float4 stD = make_float4(0.f, 0.f, 0.f, 0.f);
    stage_load<C, CHV>(lrow, d2row, 0, T, lane, st, stD);
    stage_write<C, CHV>(ringL, ringD, 0, lane, st, stD);
    stage_load<C, CHV>(lrow, d2row, 32, T, lane, st, stD);
    stage_write<C, CHV>(ringL, ringD, 32, lane, st, stD);
    stage_load<C, CHV>(lrow, d2row, 64, T, lane, st, stD);  // chunk 2 in flight

    float gA[NST], gB[NST], dA, dB;
    gather_row<NST, C>(ringL, ringD, 0, clsoff, gA, dA);
    gather_row<NST, C>(ringL, ringD, 1, clsoff, gB, dB);

    float a[NST];
#pragma unroll
    for (int s = 0; s < NST; ++s) a[s] = 0.f;
    int E = 0;
    float capA = 0.f, capB = 0.f;
    int capEA = 0, capEB = 0;

    const int NCH = (T + 31) >> 5;
    for (int c = 0; c < NCH; ++c) {
        int t0 = c << 5;
        int half = min(32, T - t0) >> 1;
        for (int j = 0; j < half; ++j) {
            int t = t0 + 2 * j;
            do_step_lin<NST>(a, E, gA, dA, validf, skipb, lane, t, t_idx, l1, l2,
                             capA, capB, capEA, capEB);
            gather_row<NST, C>(ringL, ringD, t + 2, clsoff, gA, dA);
            do_step_lin<NST>(a, E, gB, dB, validf, skipb, lane, t + 1, t_idx, l1, l2,
                             capA, capB, capEA, capEB);
            gather_row<NST, C>(ringL, ringD, t + 3, clsoff, gB, dB);
            if (j == 14 && c + 2 < NCH) {
                stage_write<C, CHV>(ringL, ringD, t0 + 64, lane, st, stD);
                if (c + 3 < NCH)
                    stage_load<C, CHV>(lrow, d2row, t0 + 96, T, lane, st, stD);
            }
        }
    }

    float vA = (capA > 0.f) ? (float)capEA + LOG2F(capA) : NEG2;
    float vB = (capB > 0.f) ? (float)capEB + LOG2F(capB) : NEG2;
    float mm = fmaxf(vA, vB);
#pragma unroll
    for (int i = 1; i < 64; i <<= 1) mm = fmaxf(mm, __shfl_xor(mm, i));
    float sum = EXP2F(vA - mm) + EXP2F(vB - mm);
#pragma unroll
    for (int i = 1; i < 64; i <<= 1) sum += __shfl_xor(sum, i);
    if (lane == 0) loss_out[b] = -(mm + LOG2F(sum)) * LN2;
}

__global__ __launch_bounds__(64) void ctc_kernel(
    const float* __restrict__ err_logits, const float* __restrict__ ph_logits,
    const int* __restrict__ err_tgt, const int* __restrict__ ph_tgt,
    const int* __restrict__ err_il, const int* __restrict__ ph_il,
    const int* __restrict__ err_tl, const int* __restrict__ ph_tl,
    const float* __restrict__ d2_err, const float* __restrict__ d2_ph,
    float* __restrict__ loss_err, float* __restrict__ loss_ph, int T) {
    __shared__ float ringL[64 * 128];
    __shared__ float ringD[64];
    int blk = blockIdx.x;
    if (blk < 32) {
        int b = blk;
        const int L = 101;
        int tl = err_tl[b];
        int l1 = min(2 * tl, L - 1);
        int l2 = max(min(2 * tl - 1, L - 1), 0);
        int t_idx = min(max(err_il[b] - 1, 0), T - 1);
        ctc_run<2, 8, 50, 1>(err_logits + (size_t)b * T * 8, d2_err + (size_t)b * T,
                             err_tgt + b * 50, T, t_idx, l1, l2, ringL, ringD,
                             loss_err, b);
    } else {
        int b = blk - 32;
        const int L = 401;
        int tl = ph_tl[b];
        int l1 = min(2 * tl, L - 1);
        int l2 = max(min(2 * tl - 1, L - 1), 0);
        int t_idx = min(max(ph_il[b] - 1, 0), T - 1);
        ctc_run<8, 128, 200, 16>(ph_logits + (size_t)b * T * 128, d2_ph + (size_t)b * T,
                                 ph_tgt + b * 200, T, t_idx, l1, l2, ringL, ringD,
                                 loss_ph, b);
    }
}

// ---------------------------------------------------------------------------
// Kernel 3: focal transform + means + total. One wave.
// ---------------------------------------------------------------------------
__global__ void final_kernel(const float* __restrict__ loss_err,
                             const float* __restrict__ loss_ph,
                             float* __restrict__ out) {
    int lane = threadIdx.x & 63;
    float fe = 0.f, fp = 0.f;
    if (lane < 32) {
        float l = fmaxf(loss_err[lane], 1e-6f);
        float pt = fminf(fmaxf(EXP2F(-l * LOG2E), 1e-6f), 1.0f);
        float om = 1.f - pt;
        fe = om * om * l;
        l = fmaxf(loss_ph[lane], 1e-6f);
        pt = fminf(fmaxf(EXP2F(-l * LOG2E), 1e-6f), 1.0f);
        om = 1.f - pt;
        fp = om * om * l;
    }
#pragma unroll
    for (int i = 1; i < 64; i <<= 1) {
        fe += __shfl_xor(fe, i);
        fp += __shfl_xor(fp, i);
    }
    if (lane == 0) {
        float err = fe / 32.f;
        float ph = fp / 32.f;
        out[0] = err + ph;
        out[1] = err;
        out[2] = ph;
    }
}

// ---------------------------------------------------------------------------
extern "C" void kernel_launch(void* const* d_in, const int* in_sizes, int n_in,
                              void* d_out, int out_size, void* d_ws, size_t ws_size,
                              hipStream_t stream) {
    const int B = 32, T = 2000;
    const float* err_logits = (const float*)d_in[0];  // [32,2000,8]
    const float* ph_logits  = (const float*)d_in[1];  // [32,2000,128]
    const int* err_tgt = (const int*)d_in[2];         // [32,50]
    const int* ph_tgt  = (const int*)d_in[3];         // [32,200]
    const int* err_il  = (const int*)d_in[4];
    const int* ph_il   = (const int*)d_in[5];
    const int* err_tl  = (const int*)d_in[6];
    const int* ph_tl   = (const int*)d_in[7];
    float* out = (float*)d_out;

    float* ws = (float*)d_ws;
    float* d2_err   = ws;                 // 64000
    float* d2_ph    = ws + 64000;         // 64000
    float* loss_err = ws + 128000;        // 32
    float* loss_ph  = ws + 128032;        // 32

    int rows = B * T;  // 64000
    denom_err_kernel<<<(rows + 255) / 256, 256, 0, stream>>>(err_logits, d2_err, rows);
    denom_ph_kernel<<<rows / 4, 256, 0, stream>>>(ph_logits, d2_ph, rows);
    ctc_kernel<<<64, 64, 0, stream>>>(err_logits, ph_logits, err_tgt, ph_tgt,
                                      err_il, ph_il, err_tl, ph_tl,
                                      d2_err, d2_ph, loss_err, loss_ph, T);
    final_kernel<<<1, 64, 0, stream>>>(loss_err, loss_ph, out);
}

// Round 5
// 672.808 us; speedup vs baseline: 1.8904x; 1.0927x over previous
//
#include <hip/hip_runtime.h>
#include <hip/hip_bf16.h>

#define LOG2E 1.4426950408889634f
#define LN2   0.6931471805599453f
#define NEG2  (-1.4426950e30f)
#define EXP2F(x) __builtin_exp2f(x)
#define LOG2F(x) __builtin_log2f(x)
#define LDEXPF(x,k) __builtin_ldexpf((x),(k))

// DPP wave_shr:1 — whole-wave shift right by one lane (lane i gets lane i-1).
// Full-rate VALU, no lgkmcnt. bound_ctrl=false => lane 0 receives `old`.
__device__ __forceinline__ float dpp_shr1_f(float x, float old) {
    return __int_as_float(__builtin_amdgcn_update_dpp(
        __float_as_int(old), __float_as_int(x), 0x138, 0xF, 0xF, false));
}
__device__ __forceinline__ int dpp_shr1_i(int x, int old) {
    return __builtin_amdgcn_update_dpp(old, x, 0x138, 0xF, 0xF, false);
}

// ---------------------------------------------------------------------------
// Kernel 1a: log2-softmax denominators for error task (C=8), one row/thread
// ---------------------------------------------------------------------------
__global__ void denom_err_kernel(const float* __restrict__ logits,
                                 float* __restrict__ d2, int rows) {
    int r = blockIdx.x * blockDim.x + threadIdx.x;
    if (r >= rows) return;
    const float* row = logits + (size_t)r * 8;
    float x[8];
#pragma unroll
    for (int i = 0; i < 8; ++i) x[i] = row[i] * LOG2E;
    float m = x[0];
#pragma unroll
    for (int i = 1; i < 8; ++i) m = fmaxf(m, x[i]);
    float s = 0.f;
#pragma unroll
    for (int i = 0; i < 8; ++i) s += EXP2F(x[i] - m);
    d2[r] = m + LOG2F(s);
}

// ---------------------------------------------------------------------------
// Kernel 1b: log2-softmax denominators for phoneme task (C=128), one row/wave
// ---------------------------------------------------------------------------
__global__ void denom_ph_kernel(const float* __restrict__ logits,
                                float* __restrict__ d2, int rows) {
    int wave = (int)((blockIdx.x * (size_t)blockDim.x + threadIdx.x) >> 6);
    int lane = threadIdx.x & 63;
    if (wave >= rows) return;
    const float* row = logits + (size_t)wave * 128;
    float x0 = row[lane] * LOG2E;
    float x1 = row[lane + 64] * LOG2E;
    float m = fmaxf(x0, x1);
#pragma unroll
    for (int i = 1; i < 64; i <<= 1) m = fmaxf(m, __shfl_xor(m, i));
    float s = EXP2F(x0 - m) + EXP2F(x1 - m);
#pragma unroll
    for (int i = 1; i < 64; i <<= 1) s += __shfl_xor(s, i);
    if (lane == 0) d2[wave] = m + LOG2F(s);
}

// ---------------------------------------------------------------------------
// CTC forward: one wave per (task, sample). LINEAR-domain alpha recursion with
// per-lane block-float (f32 mantissas + per-lane int exponent E). Cross-lane
// neighbor values via DPP wave_shr:1 (VALU; keeps lgkmcnt free for gathers).
// Logits staged via 64-row LDS ring (float4 global loads issued ~2 chunks
// ahead), gathers register-prefetched 2 steps ahead.
// ---------------------------------------------------------------------------
template <int NST, int C>
__device__ __forceinline__ void gather_row(const float* ringL, const float* ringD,
                                           int row, const int (&clsoff)[NST],
                                           float (&g)[NST], float& gd) {
    int base = (row & 63) * C;
#pragma unroll
    for (int s = 0; s < NST; ++s) g[s] = ringL[base + clsoff[s]];
    gd = ringD[row & 63];
}

template <int C, int CHV>
__device__ __forceinline__ void stage_load(const float* __restrict__ lrow,
                                           const float* __restrict__ d2row,
                                           int t0, int T, int lane,
                                           float4 (&st)[CHV], float4& stD) {
#pragma unroll
    for (int j = 0; j < CHV; ++j) {
        int e = t0 * C + (j * 64 + lane) * 4;
        e = min(e, T * C - 4);
        st[j] = *(const float4*)(lrow + e);
    }
    if (lane < 8) {
        int e = t0 + lane * 4;
        e = min(e, T - 4);
        stD = *(const float4*)(d2row + e);
    }
}

template <int C, int CHV>
__device__ __forceinline__ void stage_write(float* ringL, float* ringD, int t0, int lane,
                                            const float4 (&st)[CHV], const float4& stD) {
    int base = (t0 & 63) * C;
#pragma unroll
    for (int j = 0; j < CHV; ++j)
        *(float4*)(ringL + base + (j * 64 + lane) * 4) = st[j];
    if (lane < 8)
        *(float4*)(ringD + (t0 & 63) + lane * 4) = stD;
}

template <int NST>
__device__ __forceinline__ void do_step_lin(
    float (&a)[NST], int& E,
    const float (&g)[NST], float gd,
    const float (&validf)[NST], const bool (&skipb)[NST],
    int lane, int t, int t_idx, int l1, int l2,
    float& capA, float& capB, int& capEA, int& capEB) {
    // emission probabilities (off critical path: depend only on gathers)
    float p[NST];
#pragma unroll
    for (int s = 0; s < NST; ++s)
        p[s] = validf[s] * EXP2F(__builtin_fmaf(g[s], LOG2E, -gd));

    if (t == 0) {
#pragma unroll
        for (int s = 0; s < NST; ++s) {
            int l = lane * NST + s;
            a[s] = (l < 2) ? p[s] : 0.f;
        }
        E = 0;
    } else {
        float top1 = dpp_shr1_f(a[NST - 1], 0.f);  // lane 0 -> 0
        int   En   = dpp_shr1_i(E, E);             // lane 0 -> own E (safe)
        int Ep = max(E, En);
        float t1 = LDEXPF(top1, En - Ep);      // shift <= 0 always
        float ao[NST];
#pragma unroll
        for (int s = 0; s < NST; ++s) ao[s] = LDEXPF(a[s], E - Ep);
        E = Ep;
#pragma unroll
        for (int s = 0; s < NST; ++s) {
            float sum;
            if (s == 0)            sum = ao[0] + t1;
            else if (s == 1)       sum = ao[1] + ao[0] + (skipb[1] ? t1 : 0.f);
            else if ((s & 1) == 0) sum = ao[s] + ao[s - 1];
            else                   sum = ao[s] + ao[s - 1] + (skipb[s] ? ao[s - 2] : 0.f);
            a[s] = sum * p[s];
        }
    }

    if (t == t_idx) {
#pragma unroll
        for (int s = 0; s < NST; ++s) {
            int l = lane * NST + s;
            if (l == l1) { capA = a[s]; capEA = E; }
            if (l == l2) { capB = a[s]; capEB = E; }
        }
    }

    if ((t & 1) == 1) {  // per-lane renorm every 2 steps (p<=1: only shrinks)
        float m = a[0];
#pragma unroll
        for (int s = 1; s < NST; ++s) m = fmaxf(m, a[s]);
        int k = ((__float_as_int(m) >> 23) & 255) - 127;
#pragma unroll
        for (int s = 0; s < NST; ++s) a[s] = LDEXPF(a[s], -k);
        E += k;
    }
}

template <int NST, int C, int S, int CHV>
__device__ __forceinline__ void ctc_run(
    const float* __restrict__ lrow, const float* __restrict__ d2row,
    const int* __restrict__ tgt, int T, int t_idx, int l1, int l2,
    float* ringL, float* ringD, float* __restrict__ loss_out, int b) {
    const int lane = threadIdx.x & 63;
    const int L = 2 * S + 1;

    int clsoff[NST];
    bool skipb[NST];
    float validf[NST];
#pragma unroll
    for (int s = 0; s < NST; ++s) {
        int l = lane * NST + s;
        bool v = (l < L);
        int li = v ? l : 0;
        int c = 0;
        bool sk = false;
        if (li & 1) {
            int i = li >> 1;
            c = tgt[i];
            if (li >= 3) sk = (c != tgt[i - 1]);
        }
        clsoff[s] = c;
        skipb[s] = sk;
        validf[s] = v ? 1.f : 0.f;
    }

    float4 st[CHV];
    float4 stD = make_float4(0.f, 0.f, 0.f, 0.f);
    stage_load<C, CHV>(lrow, d2row, 0, T, lane, st, stD);
    stage_write<C, CHV>(ringL, ringD, 0, lane, st, stD);
    stage_load<C, CHV>(lrow, d2row, 32, T, lane, st, stD);
    stage_write<C, CHV>(ringL, ringD, 32, lane, st, stD);
    stage_load<C, CHV>(lrow, d2row, 64, T, lane, st, stD);  // chunk 2 in flight

    float gA[NST], gB[NST], dA, dB;
    gather_row<NST, C>(ringL, ringD, 0, clsoff, gA, dA);
    gather_row<NST, C>(ringL, ringD, 1, clsoff, gB, dB);

    float a[NST];
#pragma unroll
    for (int s = 0; s < NST; ++s) a[s] = 0.f;
    int E = 0;
    float capA = 0.f, capB = 0.f;
    int capEA = 0, capEB = 0;

    const int NCH = (T + 31) >> 5;
    for (int c = 0; c < NCH; ++c) {
        int t0 = c << 5;
        int half = min(32, T - t0) >> 1;
        for (int j = 0; j < half; ++j) {
            int t = t0 + 2 * j;
            do_step_lin<NST>(a, E, gA, dA, validf, skipb, lane, t, t_idx, l1, l2,
                             capA, capB, capEA, capEB);
            gather_row<NST, C>(ringL, ringD, t + 2, clsoff, gA, dA);
            do_step_lin<NST>(a, E, gB, dB, validf, skipb, lane, t + 1, t_idx, l1, l2,
                             capA, capB, capEA, capEB);
            gather_row<NST, C>(ringL, ringD, t + 3, clsoff, gB, dB);
            if (j == 14 && c + 2 < NCH) {
                stage_write<C, CHV>(ringL, ringD, t0 + 64, lane, st, stD);
                if (c + 3 < NCH)
                    stage_load<C, CHV>(lrow, d2row, t0 + 96, T, lane, st, stD);
            }
        }
    }

    float vA = (capA > 0.f) ? (float)capEA + LOG2F(capA) : NEG2;
    float vB = (capB > 0.f) ? (float)capEB + LOG2F(capB) : NEG2;
    float mm = fmaxf(vA, vB);
#pragma unroll
    for (int i = 1; i < 64; i <<= 1) mm = fmaxf(mm, __shfl_xor(mm, i));
    float sum = EXP2F(vA - mm) + EXP2F(vB - mm);
#pragma unroll
    for (int i = 1; i < 64; i <<= 1) sum += __shfl_xor(sum, i);
    if (lane == 0) loss_out[b] = -(mm + LOG2F(sum)) * LN2;
}

__global__ __launch_bounds__(64) void ctc_kernel(
    const float* __restrict__ err_logits, const float* __restrict__ ph_logits,
    const int* __restrict__ err_tgt, const int* __restrict__ ph_tgt,
    const int* __restrict__ err_il, const int* __restrict__ ph_il,
    const int* __restrict__ err_tl, const int* __restrict__ ph_tl,
    const float* __restrict__ d2_err, const float* __restrict__ d2_ph,
    float* __restrict__ loss_err, float* __restrict__ loss_ph, int T) {
    __shared__ float ringL[64 * 128];
    __shared__ float ringD[64];
    int blk = blockIdx.x;
    if (blk < 32) {
        int b = blk;
        const int L = 101;
        int tl = err_tl[b];
        int l1 = min(2 * tl, L - 1);
        int l2 = max(min(2 * tl - 1, L - 1), 0);
        int t_idx = min(max(err_il[b] - 1, 0), T - 1);
        ctc_run<2, 8, 50, 1>(err_logits + (size_t)b * T * 8, d2_err + (size_t)b * T,
                             err_tgt + b * 50, T, t_idx, l1, l2, ringL, ringD,
                             loss_err, b);
    } else {
        int b = blk - 32;
        const int L = 401;
        int tl = ph_tl[b];
        int l1 = min(2 * tl, L - 1);
        int l2 = max(min(2 * tl - 1, L - 1), 0);
        int t_idx = min(max(ph_il[b] - 1, 0), T - 1);
        ctc_run<8, 128, 200, 16>(ph_logits + (size_t)b * T * 128, d2_ph + (size_t)b * T,
                                 ph_tgt + b * 200, T, t_idx, l1, l2, ringL, ringD,
                                 loss_ph, b);
    }
}

// ---------------------------------------------------------------------------
// Kernel 3: focal transform + means + total. One wave.
// ---------------------------------------------------------------------------
__global__ void final_kernel(const float* __restrict__ loss_err,
                             const float* __restrict__ loss_ph,
                             float* __restrict__ out) {
    int lane = threadIdx.x & 63;
    float fe = 0.f, fp = 0.f;
    if (lane < 32) {
        float l = fmaxf(loss_err[lane], 1e-6f);
        float pt = fminf(fmaxf(EXP2F(-l * LOG2E), 1e-6f), 1.0f);
        float om = 1.f - pt;
        fe = om * om * l;
        l = fmaxf(loss_ph[lane], 1e-6f);
        pt = fminf(fmaxf(EXP2F(-l * LOG2E), 1e-6f), 1.0f);
        om = 1.f - pt;
        fp = om * om * l;
    }
#pragma unroll
    for (int i = 1; i < 64; i <<= 1) {
        fe += __shfl_xor(fe, i);
        fp += __shfl_xor(fp, i);
    }
    if (lane == 0) {
        float err = fe / 32.f;
        float ph = fp / 32.f;
        out[0] = err + ph;
        out[1] = err;
        out[2] = ph;
    }
}

// ---------------------------------------------------------------------------
extern "C" void kernel_launch(void* const* d_in, const int* in_sizes, int n_in,
                              void* d_out, int out_size, void* d_ws, size_t ws_size,
                              hipStream_t stream) {
    const int B = 32, T = 2000;
    const float* err_logits = (const float*)d_in[0];  // [32,2000,8]
    const float* ph_logits  = (const float*)d_in[1];  // [32,2000,128]
    const int* err_tgt = (const int*)d_in[2];         // [32,50]
    const int* ph_tgt  = (const int*)d_in[3];         // [32,200]
    const int* err_il  = (const int*)d_in[4];
    const int* ph_il   = (const int*)d_in[5];
    const int* err_tl  = (const int*)d_in[6];
    const int* ph_tl   = (const int*)d_in[7];
    float* out = (float*)d_out;

    float* ws = (float*)d_ws;
    float* d2_err   = ws;                 // 64000
    float* d2_ph    = ws + 64000;         // 64000
    float* loss_err = ws + 128000;        // 32
    float* loss_ph  = ws + 128032;        // 32

    int rows = B * T;  // 64000
    denom_err_kernel<<<(rows + 255) / 256, 256, 0, stream>>>(err_logits, d2_err, rows);
    denom_ph_kernel<<<rows / 4, 256, 0, stream>>>(ph_logits, d2_ph, rows);
    ctc_kernel<<<64, 64, 0, stream>>>(err_logits, ph_logits, err_tgt, ph_tgt,
                                      err_il, ph_il, err_tl, ph_tl,
                                      d2_err, d2_ph, loss_err, loss_ph, T);
    final_kernel<<<1, 64, 0, stream>>>(loss_err, loss_ph, out);
}

// Round 6
// 330.890 us; speedup vs baseline: 3.8439x; 2.0333x over previous
//
#include <hip/hip_runtime.h>
#include <hip/hip_bf16.h>

#define LOG2E 1.4426950408889634f
#define LN2   0.6931471805599453f
#define NEG2  (-1.4426950e30f)
#define EXP2F(x) __builtin_exp2f(x)
#define LOG2F(x) __builtin_log2f(x)
#define LDEXPF(x,k) __builtin_ldexpf((x),(k))

// DPP wave_shr:1 — whole-wave shift right one lane (lane i gets lane i-1).
// Full-rate VALU, no lgkmcnt. bound_ctrl=false => lane 0 receives `old`.
__device__ __forceinline__ float dpp_shr1_f(float x, float old) {
    return __int_as_float(__builtin_amdgcn_update_dpp(
        __float_as_int(old), __float_as_int(x), 0x138, 0xF, 0xF, false));
}
__device__ __forceinline__ int dpp_shr1_i(int x, int old) {
    return __builtin_amdgcn_update_dpp(old, x, 0x138, 0xF, 0xF, false);
}

__device__ __forceinline__ unsigned bf16r(float x) {  // round-half-up bf16
    return (__float_as_uint(x) + 0x8000u) >> 16;
}

// ===========================================================================
// FAST PATH: parallel emission-probability precompute + lean serial recursion
// ===========================================================================

// One wave per (b,t) row of phoneme logits (C=128). Computes softmax denom,
// then p for extended states l=0..400 (even=blank cls 0, odd=tgt[l>>1]),
// bf16-packed into P[r*512 + l], zeros for l>400.
__global__ __launch_bounds__(256) void ph_prob_kernel(
    const float* __restrict__ logits, const int* __restrict__ tgt,
    unsigned short* __restrict__ P) {
    int wid = threadIdx.x >> 6, lane = threadIdx.x & 63;
    int r = blockIdx.x * 4 + wid;               // [0, 64000)
    int b = r / 2000;
    const float* row = logits + (size_t)r * 128;
    __shared__ float ylds[4][128];
    float y0 = row[lane] * LOG2E;
    float y1 = row[lane + 64] * LOG2E;
    ylds[wid][lane] = y0;
    ylds[wid][lane + 64] = y1;
    float m = fmaxf(y0, y1);
#pragma unroll
    for (int i = 1; i < 64; i <<= 1) m = fmaxf(m, __shfl_xor(m, i));
    float s = EXP2F(y0 - m) + EXP2F(y1 - m);
#pragma unroll
    for (int i = 1; i < 64; i <<= 1) s += __shfl_xor(s, i);
    float d2 = m + LOG2F(s);

    int c[4];
#pragma unroll
    for (int k = 0; k < 4; ++k) {
        int i = min(4 * lane + k, 199);
        c[k] = tgt[b * 200 + i];
    }
    float pb = EXP2F(ylds[wid][0] - d2);
    float po[4];
#pragma unroll
    for (int k = 0; k < 4; ++k) po[k] = EXP2F(ylds[wid][c[k]] - d2);

    unsigned h[8];
#pragma unroll
    for (int s2 = 0; s2 < 8; ++s2) {
        int l = 8 * lane + s2;
        float v = (s2 & 1) ? po[s2 >> 1] : pb;
        h[s2] = (l <= 400) ? bf16r(v) : 0u;
    }
    uint4 u;
    u.x = h[0] | (h[1] << 16);
    u.y = h[2] | (h[3] << 16);
    u.z = h[4] | (h[5] << 16);
    u.w = h[6] | (h[7] << 16);
    *(uint4*)(P + (size_t)r * 512 + lane * 8) = u;
}

// One wave per (b,t) row of error logits (C=8). States l=0..100, padded 128.
__global__ __launch_bounds__(256) void err_prob_kernel(
    const float* __restrict__ logits, const int* __restrict__ tgt,
    unsigned short* __restrict__ P) {
    int wid = threadIdx.x >> 6, lane = threadIdx.x & 63;
    int r = blockIdx.x * 4 + wid;
    int b = r / 2000;
    const float* row = logits + (size_t)r * 8;
    __shared__ float ylds[4][8];
    float y = (lane < 8) ? row[lane] * LOG2E : -3.0e38f;
    if (lane < 8) ylds[wid][lane] = y;
    float m = y;
#pragma unroll
    for (int i = 1; i < 64; i <<= 1) m = fmaxf(m, __shfl_xor(m, i));
    float s = EXP2F(y - m);
#pragma unroll
    for (int i = 1; i < 64; i <<= 1) s += __shfl_xor(s, i);
    float d2 = m + LOG2F(s);

    int cc = tgt[b * 50 + min(lane, 49)];
    float pb = EXP2F(ylds[wid][0] - d2);
    float pod = EXP2F(ylds[wid][cc] - d2);
    int l0 = 2 * lane;
    unsigned h0 = (l0 <= 100) ? bf16r(pb) : 0u;
    unsigned h1 = (l0 + 1 <= 100) ? bf16r(pod) : 0u;
    *(unsigned*)(P + (size_t)r * 128 + lane * 2) = h0 | (h1 << 16);
}

// --- serial recursion step on precomputed probabilities -------------------
template <int NST>
__device__ __forceinline__ void do_step_p(
    float (&a)[NST], int& E, const float (&p)[NST], const bool (&skipb)[NST],
    int lane, int t, int t_idx, int l1, int l2,
    float& capA, float& capB, int& capEA, int& capEB) {
    if (t == 0) {
#pragma unroll
        for (int s = 0; s < NST; ++s) {
            int l = lane * NST + s;
            a[s] = (l < 2) ? p[s] : 0.f;
        }
        E = 0;
    } else {
        float top1 = dpp_shr1_f(a[NST - 1], 0.f);
        int   En   = dpp_shr1_i(E, E);
        int Ep = max(E, En);
        float t1 = LDEXPF(top1, En - Ep);
        float ao[NST];
#pragma unroll
        for (int s = 0; s < NST; ++s) ao[s] = LDEXPF(a[s], E - Ep);
        E = Ep;
#pragma unroll
        for (int s = 0; s < NST; ++s) {
            float sum;
            if (s == 0)            sum = ao[0] + t1;
            else if (s == 1)       sum = ao[1] + ao[0] + (skipb[1] ? t1 : 0.f);
            else if ((s & 1) == 0) sum = ao[s] + ao[s - 1];
            else                   sum = ao[s] + ao[s - 1] + (skipb[s] ? ao[s - 2] : 0.f);
            a[s] = sum * p[s];
        }
    }
    if (t == t_idx) {
#pragma unroll
        for (int s = 0; s < NST; ++s) {
            int l = lane * NST + s;
            if (l == l1) { capA = a[s]; capEA = E; }
            if (l == l2) { capB = a[s]; capEB = E; }
        }
    }
    if ((t & 1) == 1) {
        float m = a[0];
#pragma unroll
        for (int s = 1; s < NST; ++s) m = fmaxf(m, a[s]);
        int k = ((__float_as_int(m) >> 23) & 255) - 127;
#pragma unroll
        for (int s = 0; s < NST; ++s) a[s] = LDEXPF(a[s], -k);
        E += k;
    }
}

__device__ __forceinline__ void finish_loss(float capA, float capB, int capEA,
                                            int capEB, int lane,
                                            float* __restrict__ loss_out, int b) {
    float vA = (capA > 0.f) ? (float)capEA + LOG2F(capA) : NEG2;
    float vB = (capB > 0.f) ? (float)capEB + LOG2F(capB) : NEG2;
    float mm = fmaxf(vA, vB);
#pragma unroll
    for (int i = 1; i < 64; i <<= 1) mm = fmaxf(mm, __shfl_xor(mm, i));
    float sum = EXP2F(vA - mm) + EXP2F(vB - mm);
#pragma unroll
    for (int i = 1; i < 64; i <<= 1) sum += __shfl_xor(sum, i);
    if (lane == 0) loss_out[b] = -(mm + LOG2F(sum)) * LN2;
}

// Phoneme serial: NST=8, row stride 512 ushorts, lane loads uint4/step,
// prefetched 8 rows ahead (covers HBM latency ~900cy).
__device__ void ctc_ph_fast(const unsigned short* __restrict__ P,
                            const int* __restrict__ tgt,
                            int T, int t_idx, int l1, int l2,
                            float* __restrict__ loss_out, int b) {
    const int lane = threadIdx.x & 63;
    bool skipb[8];
#pragma unroll
    for (int s = 0; s < 8; ++s) {
        int l = lane * 8 + s;
        bool sk = false;
        if ((l & 1) && l >= 3 && l <= 400) {
            int i = l >> 1;
            sk = (tgt[i] != tgt[i - 1]);
        }
        skipb[s] = sk;
    }
    const unsigned short* Pb = P + (size_t)b * T * 512;
    uint4 q[8];
#pragma unroll
    for (int j = 0; j < 8; ++j)
        q[j] = *((const uint4*)(Pb + (size_t)min(j, T - 1) * 512) + lane);

    float a[8];
#pragma unroll
    for (int s = 0; s < 8; ++s) a[s] = 0.f;
    int E = 0;
    float capA = 0.f, capB = 0.f;
    int capEA = 0, capEB = 0;

    int nb = T >> 3;  // T=2000 -> 250
    for (int bi = 0; bi < nb; ++bi) {
        int t0 = bi << 3;
        uint4 qn[8];
#pragma unroll
        for (int j = 0; j < 8; ++j) {
            int tn = min(t0 + 8 + j, T - 1);
            qn[j] = *((const uint4*)(Pb + (size_t)tn * 512) + lane);
        }
#pragma unroll
        for (int j = 0; j < 8; ++j) {
            int t = t0 + j;
            float p[8];
            p[0] = __uint_as_float(q[j].x << 16);
            p[1] = __uint_as_float(q[j].x & 0xFFFF0000u);
            p[2] = __uint_as_float(q[j].y << 16);
            p[3] = __uint_as_float(q[j].y & 0xFFFF0000u);
            p[4] = __uint_as_float(q[j].z << 16);
            p[5] = __uint_as_float(q[j].z & 0xFFFF0000u);
            p[6] = __uint_as_float(q[j].w << 16);
            p[7] = __uint_as_float(q[j].w & 0xFFFF0000u);
            do_step_p<8>(a, E, p, skipb, lane, t, t_idx, l1, l2,
                         capA, capB, capEA, capEB);
        }
#pragma unroll
        for (int j = 0; j < 8; ++j) q[j] = qn[j];
    }
    finish_loss(capA, capB, capEA, capEB, lane, loss_out, b);
}

// Error serial: NST=2, row stride 128 ushorts, lane loads uint/step.
__device__ void ctc_err_fast(const unsigned short* __restrict__ P,
                             const int* __restrict__ tgt,
                             int T, int t_idx, int l1, int l2,
                             float* __restrict__ loss_out, int b) {
    const int lane = threadIdx.x & 63;
    bool skipb[2];
    skipb[0] = false;
    {
        int l = lane * 2 + 1;
        bool sk = false;
        if (l >= 3 && l <= 100) {
            int i = l >> 1;
            sk = (tgt[i] != tgt[i - 1]);
        }
        skipb[1] = sk;
    }
    const unsigned short* Pb = P + (size_t)b * T * 128;
    unsigned q[8];
#pragma unroll
    for (int j = 0; j < 8; ++j)
        q[j] = *((const unsigned*)(Pb + (size_t)min(j, T - 1) * 128) + lane);

    float a[2];
    a[0] = 0.f; a[1] = 0.f;
    int E = 0;
    float capA = 0.f, capB = 0.f;
    int capEA = 0, capEB = 0;

    int nb = T >> 3;
    for (int bi = 0; bi < nb; ++bi) {
        int t0 = bi << 3;
        unsigned qn[8];
#pragma unroll
        for (int j = 0; j < 8; ++j) {
            int tn = min(t0 + 8 + j, T - 1);
            qn[j] = *((const unsigned*)(Pb + (size_t)tn * 128) + lane);
        }
#pragma unroll
        for (int j = 0; j < 8; ++j) {
            int t = t0 + j;
            float p[2];
            p[0] = __uint_as_float(q[j] << 16);
            p[1] = __uint_as_float(q[j] & 0xFFFF0000u);
            do_step_p<2>(a, E, p, skipb, lane, t, t_idx, l1, l2,
                         capA, capB, capEA, capEB);
        }
#pragma unroll
        for (int j = 0; j < 8; ++j) q[j] = qn[j];
    }
    finish_loss(capA, capB, capEA, capEB, lane, loss_out, b);
}

__global__ __launch_bounds__(64) void ctc2_kernel(
    const unsigned short* __restrict__ Perr, const unsigned short* __restrict__ Pph,
    const int* __restrict__ err_tgt, const int* __restrict__ ph_tgt,
    const int* __restrict__ err_il, const int* __restrict__ ph_il,
    const int* __restrict__ err_tl, const int* __restrict__ ph_tl,
    float* __restrict__ loss_err, float* __restrict__ loss_ph, int T) {
    int blk = blockIdx.x;
    if (blk < 32) {
        int b = blk;
        const int L = 101;
        int tl = err_tl[b];
        int l1 = min(2 * tl, L - 1);
        int l2 = max(min(2 * tl - 1, L - 1), 0);
        int t_idx = min(max(err_il[b] - 1, 0), T - 1);
        ctc_err_fast(Perr, err_tgt + b * 50, T, t_idx, l1, l2, loss_err, b);
    } else {
        int b = blk - 32;
        const int L = 401;
        int tl = ph_tl[b];
        int l1 = min(2 * tl, L - 1);
        int l2 = max(min(2 * tl - 1, L - 1), 0);
        int t_idx = min(max(ph_il[b] - 1, 0), T - 1);
        ctc_ph_fast(Pph, ph_tgt + b * 200, T, t_idx, l1, l2, loss_ph, b);
    }
}

// ===========================================================================
// FALLBACK PATH (round-5, passing): LDS-ring staged gathers, used if ws small
// ===========================================================================
__global__ void denom_err_kernel(const float* __restrict__ logits,
                                 float* __restrict__ d2, int rows) {
    int r = blockIdx.x * blockDim.x + threadIdx.x;
    if (r >= rows) return;
    const float* row = logits + (size_t)r * 8;
    float x[8];
#pragma unroll
    for (int i = 0; i < 8; ++i) x[i] = row[i] * LOG2E;
    float m = x[0];
#pragma unroll
    for (int i = 1; i < 8; ++i) m = fmaxf(m, x[i]);
    float s = 0.f;
#pragma unroll
    for (int i = 0; i < 8; ++i) s += EXP2F(x[i] - m);
    d2[r] = m + LOG2F(s);
}

__global__ void denom_ph_kernel(const float* __restrict__ logits,
                                float* __restrict__ d2, int rows) {
    int wave = (int)((blockIdx.x * (size_t)blockDim.x + threadIdx.x) >> 6);
    int lane = threadIdx.x & 63;
    if (wave >= rows) return;
    const float* row = logits + (size_t)wave * 128;
    float x0 = row[lane] * LOG2E;
    float x1 = row[lane + 64] * LOG2E;
    float m = fmaxf(x0, x1);
#pragma unroll
    for (int i = 1; i < 64; i <<= 1) m = fmaxf(m, __shfl_xor(m, i));
    float s = EXP2F(x0 - m) + EXP2F(x1 - m);
#pragma unroll
    for (int i = 1; i < 64; i <<= 1) s += __shfl_xor(s, i);
    if (lane == 0) d2[wave] = m + LOG2F(s);
}

template <int NST, int C>
__device__ __forceinline__ void gather_row(const float* ringL, const float* ringD,
                                           int row, const int (&clsoff)[NST],
                                           float (&g)[NST], float& gd) {
    int base = (row & 63) * C;
#pragma unroll
    for (int s = 0; s < NST; ++s) g[s] = ringL[base + clsoff[s]];
    gd = ringD[row & 63];
}

template <int C, int CHV>
__device__ __forceinline__ void stage_load(const float* __restrict__ lrow,
                                           const float* __restrict__ d2row,
                                           int t0, int T, int lane,
                                           float4 (&st)[CHV], float4& stD) {
#pragma unroll
    for (int j = 0; j < CHV; ++j) {
        int e = t0 * C + (j * 64 + lane) * 4;
        e = min(e, T * C - 4);
        st[j] = *(const float4*)(lrow + e);
    }
    if (lane < 8) {
        int e = t0 + lane * 4;
        e = min(e, T - 4);
        stD = *(const float4*)(d2row + e);
    }
}

template <int C, int CHV>
__device__ __forceinline__ void stage_write(float* ringL, float* ringD, int t0, int lane,
                                            const float4 (&st)[CHV], const float4& stD) {
    int base = (t0 & 63) * C;
#pragma unroll
    for (int j = 0; j < CHV; ++j)
        *(float4*)(ringL + base + (j * 64 + lane) * 4) = st[j];
    if (lane < 8)
        *(float4*)(ringD + (t0 & 63) + lane * 4) = stD;
}

template <int NST>
__device__ __forceinline__ void do_step_lin(
    float (&a)[NST], int& E,
    const float (&g)[NST], float gd,
    const float (&validf)[NST], const bool (&skipb)[NST],
    int lane, int t, int t_idx, int l1, int l2,
    float& capA, float& capB, int& capEA, int& capEB) {
    float p[NST];
#pragma unroll
    for (int s = 0; s < NST; ++s)
        p[s] = validf[s] * EXP2F(__builtin_fmaf(g[s], LOG2E, -gd));
    if (t == 0) {
#pragma unroll
        for (int s = 0; s < NST; ++s) {
            int l = lane * NST + s;
            a[s] = (l < 2) ? p[s] : 0.f;
        }
        E = 0;
    } else {
        float top1 = dpp_shr1_f(a[NST - 1], 0.f);
        int   En   = dpp_shr1_i(E, E);
        int Ep = max(E, En);
        float t1 = LDEXPF(top1, En - Ep);
        float ao[NST];
#pragma unroll
        for (int s = 0; s < NST; ++s) ao[s] = LDEXPF(a[s], E - Ep);
        E = Ep;
#pragma unroll
        for (int s = 0; s < NST; ++s) {
            float sum;
            if (s == 0)            sum = ao[0] + t1;
            else if (s == 1)       sum = ao[1] + ao[0] + (skipb[1] ? t1 : 0.f);
            else if ((s & 1) == 0) sum = ao[s] + ao[s - 1];
            else                   sum = ao[s] + ao[s - 1] + (skipb[s] ? ao[s - 2] : 0.f);
            a[s] = sum * p[s];
        }
    }
    if (t == t_idx) {
#pragma unroll
        for (int s = 0; s < NST; ++s) {
            int l = lane * NST + s;
            if (l == l1) { capA = a[s]; capEA = E; }
            if (l == l2) { capB = a[s]; capEB = E; }
        }
    }
    if ((t & 1) == 1) {
        float m = a[0];
#pragma unroll
        for (int s = 1; s < NST; ++s) m = fmaxf(m, a[s]);
        int k = ((__float_as_int(m) >> 23) & 255) - 127;
#pragma unroll
        for (int s = 0; s < NST; ++s) a[s] = LDEXPF(a[s], -k);
        E += k;
    }
}

template <int NST, int C, int S, int CHV>
__device__ __forceinline__ void ctc_run(
    const float* __restrict__ lrow, const float* __restrict__ d2row,
    const int* __restrict__ tgt, int T, int t_idx, int l1, int l2,
    float* ringL, float* ringD, float* __restrict__ loss_out, int b) {
    const int lane = threadIdx.x & 63;
    const int L = 2 * S + 1;
    int clsoff[NST];
    bool skipb[NST];
    float validf[NST];
#pragma unroll
    for (int s = 0; s < NST; ++s) {
        int l = lane * NST + s;
        bool v = (l < L);
        int li = v ? l : 0;
        int c = 0;
        bool sk = false;
        if (li & 1) {
            int i = li >> 1;
            c = tgt[i];
            if (li >= 3) sk = (c != tgt[i - 1]);
        }
        clsoff[s] = c;
        skipb[s] = sk;
        validf[s] = v ? 1.f : 0.f;
    }
    float4 st[CHV];
    float4 stD = make_float4(0.f, 0.f, 0.f, 0.f);
    stage_load<C, CHV>(lrow, d2row, 0, T, lane, st, stD);
    stage_write<C, CHV>(ringL, ringD, 0, lane, st, stD);
    stage_load<C, CHV>(lrow, d2row, 32, T, lane, st, stD);
    stage_write<C, CHV>(ringL, ringD, 32, lane, st, stD);
    stage_load<C, CHV>(lrow, d2row, 64, T, lane, st, stD);
    float gA[NST], gB[NST], dA, dB;
    gather_row<NST, C>(ringL, ringD, 0, clsoff, gA, dA);
    gather_row<NST, C>(ringL, ringD, 1, clsoff, gB, dB);
    float a[NST];
#pragma unroll
    for (int s = 0; s < NST; ++s) a[s] = 0.f;
    int E = 0;
    float capA = 0.f, capB = 0.f;
    int capEA = 0, capEB = 0;
    const int NCH = (T + 31) >> 5;
    for (int c = 0; c < NCH; ++c) {
        int t0 = c << 5;
        int half = min(32, T - t0) >> 1;
        for (int j = 0; j < half; ++j) {
            int t = t0 + 2 * j;
            do_step_lin<NST>(a, E, gA, dA, validf, skipb, lane, t, t_idx, l1, l2,
                             capA, capB, capEA, capEB);
            gather_row<NST, C>(ringL, ringD, t + 2, clsoff, gA, dA);
            do_step_lin<NST>(a, E, gB, dB, validf, skipb, lane, t + 1, t_idx, l1, l2,
                             capA, capB, capEA, capEB);
            gather_row<NST, C>(ringL, ringD, t + 3, clsoff, gB, dB);
            if (j == 14 && c + 2 < NCH) {
                stage_write<C, CHV>(ringL, ringD, t0 + 64, lane, st, stD);
                if (c + 3 < NCH)
                    stage_load<C, CHV>(lrow, d2row, t0 + 96, T, lane, st, stD);
            }
        }
    }
    float vA = (capA > 0.f) ? (float)capEA + LOG2F(capA) : NEG2;
    float vB = (capB > 0.f) ? (float)capEB + LOG2F(capB) : NEG2;
    float mm = fmaxf(vA, vB);
#pragma unroll
    for (int i = 1; i < 64; i <<= 1) mm = fmaxf(mm, __shfl_xor(mm, i));
    float sum = EXP2F(vA - mm) + EXP2F(vB - mm);
#pragma unroll
    for (int i = 1; i < 64; i <<= 1) sum += __shfl_xor(sum, i);
    if (lane == 0) loss_out[b] = -(mm + LOG2F(sum)) * LN2;
}

__global__ __launch_bounds__(64) void ctc_kernel(
    const float* __restrict__ err_logits, const float* __restrict__ ph_logits,
    const int* __restrict__ err_tgt, const int* __restrict__ ph_tgt,
    const int* __restrict__ err_il, const int* __restrict__ ph_il,
    const int* __restrict__ err_tl, const int* __restrict__ ph_tl,
    const float* __restrict__ d2_err, const float* __restrict__ d2_ph,
    float* __restrict__ loss_err, float* __restrict__ loss_ph, int T) {
    __shared__ float ringL[64 * 128];
    __shared__ float ringD[64];
    int blk = blockIdx.x;
    if (blk < 32) {
        int b = blk;
        const int L = 101;
        int tl = err_tl[b];
        int l1 = min(2 * tl, L - 1);
        int l2 = max(min(2 * tl - 1, L - 1), 0);
        int t_idx = min(max(err_il[b] - 1, 0), T - 1);
        ctc_run<2, 8, 50, 1>(err_logits + (size_t)b * T * 8, d2_err + (size_t)b * T,
                             err_tgt + b * 50, T, t_idx, l1, l2, ringL, ringD,
                             loss_err, b);
    } else {
        int b = blk - 32;
        const int L = 401;
        int tl = ph_tl[b];
        int l1 = min(2 * tl, L - 1);
        int l2 = max(min(2 * tl - 1, L - 1), 0);
        int t_idx = min(max(ph_il[b] - 1, 0), T - 1);
        ctc_run<8, 128, 200, 16>(ph_logits + (size_t)b * T * 128, d2_ph + (size_t)b * T,
                                 ph_tgt + b * 200, T, t_idx, l1, l2, ringL, ringD,
                                 loss_ph, b);
    }
}

// ---------------------------------------------------------------------------
// Final: focal transform + means + total. One wave.
// ---------------------------------------------------------------------------
__global__ void final_kernel(const float* __restrict__ loss_err,
                             const float* __restrict__ loss_ph,
                             float* __restrict__ out) {
    int lane = threadIdx.x & 63;
    float fe = 0.f, fp = 0.f;
    if (lane < 32) {
        float l = fmaxf(loss_err[lane], 1e-6f);
        float pt = fminf(fmaxf(EXP2F(-l * LOG2E), 1e-6f), 1.0f);
        float om = 1.f - pt;
        fe = om * om * l;
        l = fmaxf(loss_ph[lane], 1e-6f);
        pt = fminf(fmaxf(EXP2F(-l * LOG2E), 1e-6f), 1.0f);
        om = 1.f - pt;
        fp = om * om * l;
    }
#pragma unroll
    for (int i = 1; i < 64; i <<= 1) {
        fe += __shfl_xor(fe, i);
        fp += __shfl_xor(fp, i);
    }
    if (lane == 0) {
        float err = fe / 32.f;
        float ph = fp / 32.f;
        out[0] = err + ph;
        out[1] = err;
        out[2] = ph;
    }
}

// ---------------------------------------------------------------------------
extern "C" void kernel_launch(void* const* d_in, const int* in_sizes, int n_in,
                              void* d_out, int out_size, void* d_ws, size_t ws_size,
                              hipStream_t stream) {
    const int B = 32, T = 2000;
    const float* err_logits = (const float*)d_in[0];  // [32,2000,8]
    const float* ph_logits  = (const float*)d_in[1];  // [32,2000,128]
    const int* err_tgt = (const int*)d_in[2];         // [32,50]
    const int* ph_tgt  = (const int*)d_in[3];         // [32,200]
    const int* err_il  = (const int*)d_in[4];
    const int* ph_il   = (const int*)d_in[5];
    const int* err_tl  = (const int*)d_in[6];
    const int* ph_tl   = (const int*)d_in[7];
    float* out = (float*)d_out;

    const size_t PH_US  = (size_t)B * T * 512;   // ushorts
    const size_t ERR_US = (size_t)B * T * 128;   // ushorts
    const size_t need = (PH_US + ERR_US) * 2 + 256;

    if (ws_size >= need) {
        // -------- fast path --------
        unsigned short* Pph  = (unsigned short*)d_ws;
        unsigned short* Perr = Pph + PH_US;
        float* loss_err = (float*)(Perr + ERR_US);
        float* loss_ph  = loss_err + 32;

        ph_prob_kernel<<<(B * T) / 4, 256, 0, stream>>>(ph_logits, ph_tgt, Pph);
        err_prob_kernel<<<(B * T) / 4, 256, 0, stream>>>(err_logits, err_tgt, Perr);
        ctc2_kernel<<<64, 64, 0, stream>>>(Perr, Pph, err_tgt, ph_tgt,
                                           err_il, ph_il, err_tl, ph_tl,
                                           loss_err, loss_ph, T);
        final_kernel<<<1, 64, 0, stream>>>(loss_err, loss_ph, out);
    } else {
        // -------- fallback (round-5) --------
        float* ws = (float*)d_ws;
        float* d2_err   = ws;
        float* d2_ph    = ws + 64000;
        float* loss_err = ws + 128000;
        float* loss_ph  = ws + 128032;
        int rows = B * T;
        denom_err_kernel<<<(rows + 255) / 256, 256, 0, stream>>>(err_logits, d2_err, rows);
        denom_ph_kernel<<<rows / 4, 256, 0, stream>>>(ph_logits, d2_ph, rows);
        ctc_kernel<<<64, 64, 0, stream>>>(err_logits, ph_logits, err_tgt, ph_tgt,
                                          err_il, ph_il, err_tl, ph_tl,
                                          d2_err, d2_ph, loss_err, loss_ph, T);
        final_kernel<<<1, 64, 0, stream>>>(loss_err, loss_ph, out);
    }
}

// Round 7
// 300.080 us; speedup vs baseline: 4.2385x; 1.1027x over previous
//
#include <hip/hip_runtime.h>
#include <hip/hip_bf16.h>

#define LOG2E 1.4426950408889634f
#define LN2   0.6931471805599453f
#define NEG2  (-1.4426950e30f)
#define EXP2F(x) __builtin_exp2f(x)
#define LOG2F(x) __builtin_log2f(x)
#define LDEXPF(x,k) __builtin_ldexpf((x),(k))

// DPP wave_shr:1 — whole-wave shift right one lane (lane i gets lane i-1).
__device__ __forceinline__ float dpp_shr1_f(float x, float old) {
    return __int_as_float(__builtin_amdgcn_update_dpp(
        __float_as_int(old), __float_as_int(x), 0x138, 0xF, 0xF, false));
}
__device__ __forceinline__ int dpp_shr1_i(int x, int old) {
    return __builtin_amdgcn_update_dpp(old, x, 0x138, 0xF, 0xF, false);
}

__device__ __forceinline__ unsigned bf16r(float x) {  // round-half-up bf16
    return (__float_as_uint(x) + 0x8000u) >> 16;
}

// async global->LDS (no VGPR data path). size literal per guide.
__device__ __forceinline__ void async16(void* lds, const void* g) {
    __builtin_amdgcn_global_load_lds(
        (const __attribute__((address_space(1))) unsigned int*)g,
        (__attribute__((address_space(3))) unsigned int*)lds, 16, 0, 0);
}
__device__ __forceinline__ void async4(void* lds, const void* g) {
    __builtin_amdgcn_global_load_lds(
        (const __attribute__((address_space(1))) unsigned int*)g,
        (__attribute__((address_space(3))) unsigned int*)lds, 4, 0, 0);
}

// ===========================================================================
// Parallel emission-probability precompute (unchanged from round 6, passing)
// ===========================================================================
__global__ __launch_bounds__(256) void ph_prob_kernel(
    const float* __restrict__ logits, const int* __restrict__ tgt,
    unsigned short* __restrict__ P) {
    int wid = threadIdx.x >> 6, lane = threadIdx.x & 63;
    int r = blockIdx.x * 4 + wid;               // [0, 64000)
    int b = r / 2000;
    const float* row = logits + (size_t)r * 128;
    __shared__ float ylds[4][128];
    float y0 = row[lane] * LOG2E;
    float y1 = row[lane + 64] * LOG2E;
    ylds[wid][lane] = y0;
    ylds[wid][lane + 64] = y1;
    float m = fmaxf(y0, y1);
#pragma unroll
    for (int i = 1; i < 64; i <<= 1) m = fmaxf(m, __shfl_xor(m, i));
    float s = EXP2F(y0 - m) + EXP2F(y1 - m);
#pragma unroll
    for (int i = 1; i < 64; i <<= 1) s += __shfl_xor(s, i);
    float d2 = m + LOG2F(s);

    int c[4];
#pragma unroll
    for (int k = 0; k < 4; ++k) {
        int i = min(4 * lane + k, 199);
        c[k] = tgt[b * 200 + i];
    }
    float pb = EXP2F(ylds[wid][0] - d2);
    float po[4];
#pragma unroll
    for (int k = 0; k < 4; ++k) po[k] = EXP2F(ylds[wid][c[k]] - d2);

    unsigned h[8];
#pragma unroll
    for (int s2 = 0; s2 < 8; ++s2) {
        int l = 8 * lane + s2;
        float v = (s2 & 1) ? po[s2 >> 1] : pb;
        h[s2] = (l <= 400) ? bf16r(v) : 0u;
    }
    uint4 u;
    u.x = h[0] | (h[1] << 16);
    u.y = h[2] | (h[3] << 16);
    u.z = h[4] | (h[5] << 16);
    u.w = h[6] | (h[7] << 16);
    *(uint4*)(P + (size_t)r * 512 + lane * 8) = u;
}

__global__ __launch_bounds__(256) void err_prob_kernel(
    const float* __restrict__ logits, const int* __restrict__ tgt,
    unsigned short* __restrict__ P) {
    int wid = threadIdx.x >> 6, lane = threadIdx.x & 63;
    int r = blockIdx.x * 4 + wid;
    int b = r / 2000;
    const float* row = logits + (size_t)r * 8;
    __shared__ float ylds[4][8];
    float y = (lane < 8) ? row[lane] * LOG2E : -3.0e38f;
    if (lane < 8) ylds[wid][lane] = y;
    float m = y;
#pragma unroll
    for (int i = 1; i < 64; i <<= 1) m = fmaxf(m, __shfl_xor(m, i));
    float s = EXP2F(y - m);
#pragma unroll
    for (int i = 1; i < 64; i <<= 1) s += __shfl_xor(s, i);
    float d2 = m + LOG2F(s);

    int cc = tgt[b * 50 + min(lane, 49)];
    float pb = EXP2F(ylds[wid][0] - d2);
    float pod = EXP2F(ylds[wid][cc] - d2);
    int l0 = 2 * lane;
    unsigned h0 = (l0 <= 100) ? bf16r(pb) : 0u;
    unsigned h1 = (l0 + 1 <= 100) ? bf16r(pod) : 0u;
    *(unsigned*)(P + (size_t)r * 128 + lane * 2) = h0 | (h1 << 16);
}

// ===========================================================================
// Producer wave: stream P rows into 32-row LDS ring, 3 chunks (24 rows) ahead.
// Counted vmcnt(8) (never 0) guarantees: all but the newest chunk retired
// before each barrier => consumer may read chunks <= k+1 during iter k.
// ===========================================================================
template <int ROWB, int W>
__device__ __forceinline__ void prod_loop(const char* __restrict__ Pb,
                                          char* ring, int NCH, int lane) {
    const char* srcl = Pb + lane * W;
#pragma unroll
    for (int c = 0; c < 3; ++c) {
#pragma unroll
        for (int r8 = 0; r8 < 8; ++r8) {
            int row = c * 8 + r8;
            if (W == 16) async16(ring + (size_t)(row & 31) * ROWB,
                                 srcl + (size_t)row * ROWB);
            else         async4 (ring + (size_t)(row & 31) * ROWB,
                                 srcl + (size_t)row * ROWB);
        }
    }
    asm volatile("s_waitcnt vmcnt(8)" ::: "memory");
    __builtin_amdgcn_sched_barrier(0);
    __builtin_amdgcn_s_barrier();
    for (int k = 0; k < NCH; ++k) {
        if (k + 3 < NCH) {
            int base = (k + 3) * 8;
#pragma unroll
            for (int r8 = 0; r8 < 8; ++r8) {
                int row = base + r8;
                if (W == 16) async16(ring + (size_t)(row & 31) * ROWB,
                                     srcl + (size_t)row * ROWB);
                else         async4 (ring + (size_t)(row & 31) * ROWB,
                                     srcl + (size_t)row * ROWB);
            }
        }
        asm volatile("s_waitcnt vmcnt(8)" ::: "memory");
        __builtin_amdgcn_sched_barrier(0);
        __builtin_amdgcn_s_barrier();
    }
}

// ===========================================================================
// Consumer: block-float linear recursion. Zero VMEM in loop; LDS reads only,
// register-prefetched 2 rows ahead. Renorm every 4 steps.
// ===========================================================================
template <int NST>
__device__ __forceinline__ void do_step_p(
    float (&a)[NST], int& E, const float (&p)[NST], const bool (&skipb)[NST],
    int lane, int t, int t_idx, int l1, int l2,
    float& capA, float& capB, int& capEA, int& capEB) {
    if (t == 0) {
#pragma unroll
        for (int s = 0; s < NST; ++s) {
            int l = lane * NST + s;
            a[s] = (l < 2) ? p[s] : 0.f;
        }
        E = 0;
    } else {
        float top1 = dpp_shr1_f(a[NST - 1], 0.f);
        int   En   = dpp_shr1_i(E, E);
        int Ep = max(E, En);
        float t1 = LDEXPF(top1, En - Ep);
        float ao[NST];
#pragma unroll
        for (int s = 0; s < NST; ++s) ao[s] = LDEXPF(a[s], E - Ep);
        E = Ep;
#pragma unroll
        for (int s = 0; s < NST; ++s) {
            float sum;
            if (s == 0)            sum = ao[0] + t1;
            else if (s == 1)       sum = ao[1] + ao[0] + (skipb[1] ? t1 : 0.f);
            else if ((s & 1) == 0) sum = ao[s] + ao[s - 1];
            else                   sum = ao[s] + ao[s - 1] + (skipb[s] ? ao[s - 2] : 0.f);
            a[s] = sum * p[s];
        }
    }
    if (t == t_idx) {
#pragma unroll
        for (int s = 0; s < NST; ++s) {
            int l = lane * NST + s;
            if (l == l1) { capA = a[s]; capEA = E; }
            if (l == l2) { capB = a[s]; capEB = E; }
        }
    }
    if ((t & 3) == 3) {   // renorm every 4 steps (p >= ~2^-12 => no flush risk)
        float m = a[0];
#pragma unroll
        for (int s = 1; s < NST; ++s) m = fmaxf(m, a[s]);
        int k = ((__float_as_int(m) >> 23) & 255) - 127;
#pragma unroll
        for (int s = 0; s < NST; ++s) a[s] = LDEXPF(a[s], -k);
        E += k;
    }
}

__device__ __forceinline__ void finish_loss(float capA, float capB, int capEA,
                                            int capEB, int lane,
                                            float* __restrict__ loss_out, int b) {
    float vA = (capA > 0.f) ? (float)capEA + LOG2F(capA) : NEG2;
    float vB = (capB > 0.f) ? (float)capEB + LOG2F(capB) : NEG2;
    float mm = fmaxf(vA, vB);
#pragma unroll
    for (int i = 1; i < 64; i <<= 1) mm = fmaxf(mm, __shfl_xor(mm, i));
    float sum = EXP2F(vA - mm) + EXP2F(vB - mm);
#pragma unroll
    for (int i = 1; i < 64; i <<= 1) sum += __shfl_xor(sum, i);
    if (lane == 0) loss_out[b] = -(mm + LOG2F(sum)) * LN2;
}

__device__ void ctc_ph_cons(const unsigned short* ring, const int* __restrict__ tgt,
                            int T, int t_idx, int l1, int l2,
                            float* __restrict__ loss_out, int b) {
    const int lane = threadIdx.x & 63;
    bool skipb[8];
#pragma unroll
    for (int s = 0; s < 8; ++s) {
        int l = lane * 8 + s;
        bool sk = false;
        if ((l & 1) && l >= 3 && l <= 400) {
            int i = l >> 1;
            sk = (tgt[i] != tgt[i - 1]);
        }
        skipb[s] = sk;
    }
    __builtin_amdgcn_s_barrier();   // prologue barrier (pairs with producer)

    auto rd = [&](int row) -> uint4 {
        return *((const uint4*)(ring + (size_t)(row & 31) * 512) + lane);
    };
    uint4 qa = rd(0), qb = rd(1);

    float a[8];
#pragma unroll
    for (int s = 0; s < 8; ++s) a[s] = 0.f;
    int E = 0;
    float capA = 0.f, capB = 0.f;
    int capEA = 0, capEB = 0;

    const int NCH = T >> 3;
    for (int k = 0; k < NCH; ++k) {
#pragma unroll
        for (int j = 0; j < 8; ++j) {
            int t = (k << 3) + j;
            uint4 cur = qa; qa = qb; qb = rd(t + 2);
            float p[8];
            p[0] = __uint_as_float(cur.x << 16);
            p[1] = __uint_as_float(cur.x & 0xFFFF0000u);
            p[2] = __uint_as_float(cur.y << 16);
            p[3] = __uint_as_float(cur.y & 0xFFFF0000u);
            p[4] = __uint_as_float(cur.z << 16);
            p[5] = __uint_as_float(cur.z & 0xFFFF0000u);
            p[6] = __uint_as_float(cur.w << 16);
            p[7] = __uint_as_float(cur.w & 0xFFFF0000u);
            do_step_p<8>(a, E, p, skipb, lane, t, t_idx, l1, l2,
                         capA, capB, capEA, capEB);
        }
        __builtin_amdgcn_s_barrier();
    }
    finish_loss(capA, capB, capEA, capEB, lane, loss_out, b);
}

__device__ void ctc_err_cons(const unsigned short* ring, const int* __restrict__ tgt,
                             int T, int t_idx, int l1, int l2,
                             float* __restrict__ loss_out, int b) {
    const int lane = threadIdx.x & 63;
    bool skipb[2];
    skipb[0] = false;
    {
        int l = lane * 2 + 1;
        bool sk = false;
        if (l >= 3 && l <= 100) {
            int i = l >> 1;
            sk = (tgt[i] != tgt[i - 1]);
        }
        skipb[1] = sk;
    }
    __builtin_amdgcn_s_barrier();

    auto rd = [&](int row) -> unsigned {
        return *((const unsigned*)(ring + (size_t)(row & 31) * 128) + lane);
    };
    unsigned qa = rd(0), qb = rd(1);

    float a[2];
    a[0] = 0.f; a[1] = 0.f;
    int E = 0;
    float capA = 0.f, capB = 0.f;
    int capEA = 0, capEB = 0;

    const int NCH = T >> 3;
    for (int k = 0; k < NCH; ++k) {
#pragma unroll
        for (int j = 0; j < 8; ++j) {
            int t = (k << 3) + j;
            unsigned cur = qa; qa = qb; qb = rd(t + 2);
            float p[2];
            p[0] = __uint_as_float(cur << 16);
            p[1] = __uint_as_float(cur & 0xFFFF0000u);
            do_step_p<2>(a, E, p, skipb, lane, t, t_idx, l1, l2,
                         capA, capB, capEA, capEB);
        }
        __builtin_amdgcn_s_barrier();
    }
    finish_loss(capA, capB, capEA, capEB, lane, loss_out, b);
}

__global__ __launch_bounds__(128) void ctc3_kernel(
    const unsigned short* __restrict__ Perr, const unsigned short* __restrict__ Pph,
    const int* __restrict__ err_tgt, const int* __restrict__ ph_tgt,
    const int* __restrict__ err_il, const int* __restrict__ ph_il,
    const int* __restrict__ err_tl, const int* __restrict__ ph_tl,
    float* __restrict__ loss_err, float* __restrict__ loss_ph, int T) {
    __shared__ unsigned short ring[32 * 512];   // 32 KiB ring
    int blk = blockIdx.x;
    int wid = threadIdx.x >> 6;
    int lane = threadIdx.x & 63;
    int NCH = T >> 3;
    if (blk < 32) {
        int b = blk;
        if (wid == 1) {
            prod_loop<256, 4>((const char*)(Perr + (size_t)b * T * 128),
                              (char*)ring, NCH, lane);
        } else {
            const int L = 101;
            int tl = err_tl[b];
            int l1 = min(2 * tl, L - 1);
            int l2 = max(min(2 * tl - 1, L - 1), 0);
            int t_idx = min(max(err_il[b] - 1, 0), T - 1);
            ctc_err_cons(ring, err_tgt + b * 50, T, t_idx, l1, l2, loss_err, b);
        }
    } else {
        int b = blk - 32;
        if (wid == 1) {
            prod_loop<1024, 16>((const char*)(Pph + (size_t)b * T * 512),
                                (char*)ring, NCH, lane);
        } else {
            const int L = 401;
            int tl = ph_tl[b];
            int l1 = min(2 * tl, L - 1);
            int l2 = max(min(2 * tl - 1, L - 1), 0);
            int t_idx = min(max(ph_il[b] - 1, 0), T - 1);
            ctc_ph_cons(ring, ph_tgt + b * 200, T, t_idx, l1, l2, loss_ph, b);
        }
    }
}

// ===========================================================================
// FALLBACK PATH (round-5, passing) — used only if ws_size too small
// ===========================================================================
__global__ void denom_err_kernel(const float* __restrict__ logits,
                                 float* __restrict__ d2, int rows) {
    int r = blockIdx.x * blockDim.x + threadIdx.x;
    if (r >= rows) return;
    const float* row = logits + (size_t)r * 8;
    float x[8];
#pragma unroll
    for (int i = 0; i < 8; ++i) x[i] = row[i] * LOG2E;
    float m = x[0];
#pragma unroll
    for (int i = 1; i < 8; ++i) m = fmaxf(m, x[i]);
    float s = 0.f;
#pragma unroll
    for (int i = 0; i < 8; ++i) s += EXP2F(x[i] - m);
    d2[r] = m + LOG2F(s);
}

__global__ void denom_ph_kernel(const float* __restrict__ logits,
                                float* __restrict__ d2, int rows) {
    int wave = (int)((blockIdx.x * (size_t)blockDim.x + threadIdx.x) >> 6);
    int lane = threadIdx.x & 63;
    if (wave >= rows) return;
    const float* row = logits + (size_t)wave * 128;
    float x0 = row[lane] * LOG2E;
    float x1 = row[lane + 64] * LOG2E;
    float m = fmaxf(x0, x1);
#pragma unroll
    for (int i = 1; i < 64; i <<= 1) m = fmaxf(m, __shfl_xor(m, i));
    float s = EXP2F(x0 - m) + EXP2F(x1 - m);
#pragma unroll
    for (int i = 1; i < 64; i <<= 1) s += __shfl_xor(s, i);
    if (lane == 0) d2[wave] = m + LOG2F(s);
}

template <int NST, int C>
__device__ __forceinline__ void gather_row(const float* ringL, const float* ringD,
                                           int row, const int (&clsoff)[NST],
                                           float (&g)[NST], float& gd) {
    int base = (row & 63) * C;
#pragma unroll
    for (int s = 0; s < NST; ++s) g[s] = ringL[base + clsoff[s]];
    gd = ringD[row & 63];
}

template <int C, int CHV>
__device__ __forceinline__ void stage_load(const float* __restrict__ lrow,
                                           const float* __restrict__ d2row,
                                           int t0, int T, int lane,
                                           float4 (&st)[CHV], float4& stD) {
#pragma unroll
    for (int j = 0; j < CHV; ++j) {
        int e = t0 * C + (j * 64 + lane) * 4;
        e = min(e, T * C - 4);
        st[j] = *(const float4*)(lrow + e);
    }
    if (lane < 8) {
        int e = t0 + lane * 4;
        e = min(e, T - 4);
        stD = *(const float4*)(d2row + e);
    }
}

template <int C, int CHV>
__device__ __forceinline__ void stage_write(float* ringL, float* ringD, int t0, int lane,
                                            const float4 (&st)[CHV], const float4& stD) {
    int base = (t0 & 63) * C;
#pragma unroll
    for (int j = 0; j < CHV; ++j)
        *(float4*)(ringL + base + (j * 64 + lane) * 4) = st[j];
    if (lane < 8)
        *(float4*)(ringD + (t0 & 63) + lane * 4) = stD;
}

template <int NST>
__device__ __forceinline__ void do_step_lin(
    float (&a)[NST], int& E,
    const float (&g)[NST], float gd,
    const float (&validf)[NST], const bool (&skipb)[NST],
    int lane, int t, int t_idx, int l1, int l2,
    float& capA, float& capB, int& capEA, int& capEB) {
    float p[NST];
#pragma unroll
    for (int s = 0; s < NST; ++s)
        p[s] = validf[s] * EXP2F(__builtin_fmaf(g[s], LOG2E, -gd));
    if (t == 0) {
#pragma unroll
        for (int s = 0; s < NST; ++s) {
            int l = lane * NST + s;
            a[s] = (l < 2) ? p[s] : 0.f;
        }
        E = 0;
    } else {
        float top1 = dpp_shr1_f(a[NST - 1], 0.f);
        int   En   = dpp_shr1_i(E, E);
        int Ep = max(E, En);
        float t1 = LDEXPF(top1, En - Ep);
        float ao[NST];
#pragma unroll
        for (int s = 0; s < NST; ++s) ao[s] = LDEXPF(a[s], E - Ep);
        E = Ep;
#pragma unroll
        for (int s = 0; s < NST; ++s) {
            float sum;
            if (s == 0)            sum = ao[0] + t1;
            else if (s == 1)       sum = ao[1] + ao[0] + (skipb[1] ? t1 : 0.f);
            else if ((s & 1) == 0) sum = ao[s] + ao[s - 1];
            else                   sum = ao[s] + ao[s - 1] + (skipb[s] ? ao[s - 2] : 0.f);
            a[s] = sum * p[s];
        }
    }
    if (t == t_idx) {
#pragma unroll
        for (int s = 0; s < NST; ++s) {
            int l = lane * NST + s;
            if (l == l1) { capA = a[s]; capEA = E; }
            if (l == l2) { capB = a[s]; capEB = E; }
        }
    }
    if ((t & 1) == 1) {
        float m = a[0];
#pragma unroll
        for (int s = 1; s < NST; ++s) m = fmaxf(m, a[s]);
        int k = ((__float_as_int(m) >> 23) & 255) - 127;
#pragma unroll
        for (int s = 0; s < NST; ++s) a[s] = LDEXPF(a[s], -k);
        E += k;
    }
}

template <int NST, int C, int S, int CHV>
__device__ __forceinline__ void ctc_run(
    const float* __restrict__ lrow, const float* __restrict__ d2row,
    const int* __restrict__ tgt, int T, int t_idx, int l1, int l2,
    float* ringL, float* ringD, float* __restrict__ loss_out, int b) {
    const int lane = threadIdx.x & 63;
    const int L = 2 * S + 1;
    int clsoff[NST];
    bool skipb[NST];
    float validf[NST];
#pragma unroll
    for (int s = 0; s < NST; ++s) {
        int l = lane * NST + s;
        bool v = (l < L);
        int li = v ? l : 0;
        int c = 0;
        bool sk = false;
        if (li & 1) {
            int i = li >> 1;
            c = tgt[i];
            if (li >= 3) sk = (c != tgt[i - 1]);
        }
        clsoff[s] = c;
        skipb[s] = sk;
        validf[s] = v ? 1.f : 0.f;
    }
    float4 st[CHV];
    float4 stD = make_float4(0.f, 0.f, 0.f, 0.f);
    stage_load<C, CHV>(lrow, d2row, 0, T, lane, st, stD);
    stage_write<C, CHV>(ringL, ringD, 0, lane, st, stD);
    stage_load<C, CHV>(lrow, d2row, 32, T, lane, st, stD);
    stage_write<C, CHV>(ringL, ringD, 32, lane, st, stD);
    stage_load<C, CHV>(lrow, d2row, 64, T, lane, st, stD);
    float gA[NST], gB[NST], dA, dB;
    gather_row<NST, C>(ringL, ringD, 0, clsoff, gA, dA);
    gather_row<NST, C>(ringL, ringD, 1, clsoff, gB, dB);
    float a[NST];
#pragma unroll
    for (int s = 0; s < NST; ++s) a[s] = 0.f;
    int E = 0;
    float capA = 0.f, capB = 0.f;
    int capEA = 0, capEB = 0;
    const int NCH = (T + 31) >> 5;
    for (int c = 0; c < NCH; ++c) {
        int t0 = c << 5;
        int half = min(32, T - t0) >> 1;
        for (int j = 0; j < half; ++j) {
            int t = t0 + 2 * j;
            do_step_lin<NST>(a, E, gA, dA, validf, skipb, lane, t, t_idx, l1, l2,
                             capA, capB, capEA, capEB);
            gather_row<NST, C>(ringL, ringD, t + 2, clsoff, gA, dA);
            do_step_lin<NST>(a, E, gB, dB, validf, skipb, lane, t + 1, t_idx, l1, l2,
                             capA, capB, capEA, capEB);
            gather_row<NST, C>(ringL, ringD, t + 3, clsoff, gB, dB);
            if (j == 14 && c + 2 < NCH) {
                stage_write<C, CHV>(ringL, ringD, t0 + 64, lane, st, stD);
                if (c + 3 < NCH)
                    stage_load<C, CHV>(lrow, d2row, t0 + 96, T, lane, st, stD);
            }
        }
    }
    float vA = (capA > 0.f) ? (float)capEA + LOG2F(capA) : NEG2;
    float vB = (capB > 0.f) ? (float)capEB + LOG2F(capB) : NEG2;
    float mm = fmaxf(vA, vB);
#pragma unroll
    for (int i = 1; i < 64; i <<= 1) mm = fmaxf(mm, __shfl_xor(mm, i));
    float sum = EXP2F(vA - mm) + EXP2F(vB - mm);
#pragma unroll
    for (int i = 1; i < 64; i <<= 1) sum += __shfl_xor(sum, i);
    if (lane == 0) loss_out[b] = -(mm + LOG2F(sum)) * LN2;
}

__global__ __launch_bounds__(64) void ctc_kernel(
    const float* __restrict__ err_logits, const float* __restrict__ ph_logits,
    const int* __restrict__ err_tgt, const int* __restrict__ ph_tgt,
    const int* __restrict__ err_il, const int* __restrict__ ph_il,
    const int* __restrict__ err_tl, const int* __restrict__ ph_tl,
    const float* __restrict__ d2_err, const float* __restrict__ d2_ph,
    float* __restrict__ loss_err, float* __restrict__ loss_ph, int T) {
    __shared__ float ringL[64 * 128];
    __shared__ float ringD[64];
    int blk = blockIdx.x;
    if (blk < 32) {
        int b = blk;
        const int L = 101;
        int tl = err_tl[b];
        int l1 = min(2 * tl, L - 1);
        int l2 = max(min(2 * tl - 1, L - 1), 0);
        int t_idx = min(max(err_il[b] - 1, 0), T - 1);
        ctc_run<2, 8, 50, 1>(err_logits + (size_t)b * T * 8, d2_err + (size_t)b * T,
                             err_tgt + b * 50, T, t_idx, l1, l2, ringL, ringD,
                             loss_err, b);
    } else {
        int b = blk - 32;
        const int L = 401;
        int tl = ph_tl[b];
        int l1 = min(2 * tl, L - 1);
        int l2 = max(min(2 * tl - 1, L - 1), 0);
        int t_idx = min(max(ph_il[b] - 1, 0), T - 1);
        ctc_run<8, 128, 200, 16>(ph_logits + (size_t)b * T * 128, d2_ph + (size_t)b * T,
                                 ph_tgt + b * 200, T, t_idx, l1, l2, ringL, ringD,
                                 loss_ph, b);
    }
}

// ---------------------------------------------------------------------------
// Final: focal transform + means + total. One wave.
// ---------------------------------------------------------------------------
__global__ void final_kernel(const float* __restrict__ loss_err,
                             const float* __restrict__ loss_ph,
                             float* __restrict__ out) {
    int lane = threadIdx.x & 63;
    float fe = 0.f, fp = 0.f;
    if (lane < 32) {
        float l = fmaxf(loss_err[lane], 1e-6f);
        float pt = fminf(fmaxf(EXP2F(-l * LOG2E), 1e-6f), 1.0f);
        float om = 1.f - pt;
        fe = om * om * l;
        l = fmaxf(loss_ph[lane], 1e-6f);
        pt = fminf(fmaxf(EXP2F(-l * LOG2E), 1e-6f), 1.0f);
        om = 1.f - pt;
        fp = om * om * l;
    }
#pragma unroll
    for (int i = 1; i < 64; i <<= 1) {
        fe += __shfl_xor(fe, i);
        fp += __shfl_xor(fp, i);
    }
    if (lane == 0) {
        float err = fe / 32.f;
        float ph = fp / 32.f;
        out[0] = err + ph;
        out[1] = err;
        out[2] = ph;
    }
}

// ---------------------------------------------------------------------------
extern "C" void kernel_launch(void* const* d_in, const int* in_sizes, int n_in,
                              void* d_out, int out_size, void* d_ws, size_t ws_size,
                              hipStream_t stream) {
    const int B = 32, T = 2000;
    const float* err_logits = (const float*)d_in[0];  // [32,2000,8]
    const float* ph_logits  = (const float*)d_in[1];  // [32,2000,128]
    const int* err_tgt = (const int*)d_in[2];         // [32,50]
    const int* ph_tgt  = (const int*)d_in[3];         // [32,200]
    const int* err_il  = (const int*)d_in[4];
    const int* ph_il   = (const int*)d_in[5];
    const int* err_tl  = (const int*)d_in[6];
    const int* ph_tl   = (const int*)d_in[7];
    float* out = (float*)d_out;

    const size_t PH_US  = (size_t)B * T * 512;   // ushorts
    const size_t ERR_US = (size_t)B * T * 128;   // ushorts
    const size_t need = (PH_US + ERR_US) * 2 + 256;

    if (ws_size >= need) {
        // -------- fast path --------
        unsigned short* Pph  = (unsigned short*)d_ws;
        unsigned short* Perr = Pph + PH_US;
        float* loss_err = (float*)(Perr + ERR_US);
        float* loss_ph  = loss_err + 32;

        ph_prob_kernel<<<(B * T) / 4, 256, 0, stream>>>(ph_logits, ph_tgt, Pph);
        err_prob_kernel<<<(B * T) / 4, 256, 0, stream>>>(err_logits, err_tgt, Perr);
        ctc3_kernel<<<64, 128, 0, stream>>>(Perr, Pph, err_tgt, ph_tgt,
                                            err_il, ph_il, err_tl, ph_tl,
                                            loss_err, loss_ph, T);
        final_kernel<<<1, 64, 0, stream>>>(loss_err, loss_ph, out);
    } else {
        // -------- fallback (round-5) --------
        float* ws = (float*)d_ws;
        float* d2_err   = ws;
        float* d2_ph    = ws + 64000;
        float* loss_err = ws + 128000;
        float* loss_ph  = ws + 128032;
        int rows = B * T;
        denom_err_kernel<<<(rows + 255) / 256, 256, 0, stream>>>(err_logits, d2_err, rows);
        denom_ph_kernel<<<rows / 4, 256, 0, stream>>>(ph_logits, d2_ph, rows);
        ctc_kernel<<<64, 64, 0, stream>>>(err_logits, ph_logits, err_tgt, ph_tgt,
                                          err_il, ph_il, err_tl, ph_tl,
                                          d2_err, d2_ph, loss_err, loss_ph, T);
        final_kernel<<<1, 64, 0, stream>>>(loss_err, loss_ph, out);
    }
}